// Round 15
// baseline (1659.315 us; speedup 1.0000x reference)
//
#include <hip/hip_runtime.h>
#include <hip/hip_bf16.h>
#include <math.h>

#define B 256
#define S 128
#define I_DIM 512
#define H 1024
#define C 10
#define WROW 1536

#define LDS_H 131072                 // 64 b-rows x 1024 k bf16, XOR-swizzled

typedef float f32x4 __attribute__((ext_vector_type(4), may_alias));
typedef __bf16 bf16x8 __attribute__((ext_vector_type(8), may_alias));
typedef unsigned int u32x4 __attribute__((ext_vector_type(4), may_alias));
typedef unsigned long long u64;
typedef unsigned long long __attribute__((may_alias)) u64a;

__device__ __forceinline__ unsigned short f2bf(float f) {
    union { float f; unsigned u; } a; a.f = f;
    return (unsigned short)((a.u + 0x7fffu + ((a.u >> 16) & 1u)) >> 16);
}
__device__ __forceinline__ float bf2f(unsigned short b) {
    union { unsigned u; float f; } a; a.u = ((unsigned)b) << 16;
    return a.f;
}
__device__ __forceinline__ float sigf(float v) { return 1.0f / (1.0f + __expf(-v)); }
__device__ __forceinline__ float tanh_fast(float v) { return 1.0f - 2.0f / (1.0f + __expf(2.0f * v)); }

// ---- fused prep: wF + wxF + ehl (verified r14) ----
__global__ void prep_build(const float* __restrict__ fwd_W,
                           const float* __restrict__ bwd_W,
                           const float* __restrict__ embed,
                           __hip_bfloat16* __restrict__ wF,
                           __hip_bfloat16* __restrict__ wxF,
                           unsigned short* __restrict__ ehl) {
    int gid = blockIdx.x * 256 + threadIdx.x;
    if (gid < 1048576) {
        int lane = gid & 63, kk = (gid >> 6) & 31, nsub = (gid >> 11) & 255, d = gid >> 19;
        int n_gl = nsub * 16 + (lane & 15);
        int j = n_gl >> 2, g = n_gl & 3;
        int k = kk * 32 + (lane >> 4) * 8;
        const float* W = d ? bwd_W : fwd_W;
        const float* src = W + (size_t)(g * 1024 + j) * WROW + I_DIM + k;
        ushort4 lo = make_ushort4(f2bf(src[0]), f2bf(src[1]), f2bf(src[2]), f2bf(src[3]));
        ushort4 hi = make_ushort4(f2bf(src[4]), f2bf(src[5]), f2bf(src[6]), f2bf(src[7]));
        ushort4* dst = (ushort4*)(wF + (size_t)gid * 8);
        dst[0] = lo; dst[1] = hi;
    } else if (gid < 1048576 + 524288) {
        int g2 = gid - 1048576;
        int lane = g2 & 63, kk = (g2 >> 6) & 15, nsub = (g2 >> 10) & 255, d = g2 >> 18;
        int n_gl = nsub * 16 + (lane & 15);
        int j = n_gl >> 2, g = n_gl & 3;
        int k = kk * 32 + (lane >> 4) * 8;
        const float* W = d ? bwd_W : fwd_W;
        const float* src = W + (size_t)(g * 1024 + j) * WROW + k;
        ushort4 lo = make_ushort4(f2bf(src[0]), f2bf(src[1]), f2bf(src[2]), f2bf(src[3]));
        ushort4 hi = make_ushort4(f2bf(src[4]), f2bf(src[5]), f2bf(src[6]), f2bf(src[7]));
        ushort4* dst = (ushort4*)(wxF + (size_t)g2 * 8);
        dst[0] = lo; dst[1] = hi;
    } else {
        int idx = gid - (1048576 + 524288);   // 0..65535
        float e = embed[idx];
        unsigned short hb = f2bf(e);
        unsigned short lb = f2bf(e - bf2f(hb));
        ehl[idx] = hb;
        ehl[65536 + idx] = lb;
    }
}

// ---- prep 2: projP[d][j][v][g] via split-bf16 MFMA (verified r10-r14) ----
__global__ __launch_bounds__(256) void projp_mfma(
        const __hip_bfloat16* __restrict__ wxF,
        const unsigned short* __restrict__ ehl,
        const float* __restrict__ fwd_b,
        const float* __restrict__ bwd_b,
        float* __restrict__ projP) {
    extern __shared__ char sm[];
    const int bid = blockIdx.x;
    const int d = bid >> 7, jt = (bid >> 2) & 31, vb = bid & 3;
    const int tid = threadIdx.x, w = tid >> 6, lane = tid & 63;
    const int l15 = lane & 15, l4 = lane >> 4;
    const int v0 = vb * 32;

    for (int i = 0; i < 16; i++) {
        int chunk = i * 256 + tid;
        int row = chunk >> 6, c16 = chunk & 63;
        int p = row >> 5, vs = v0 + (row & 31);
        u32x4 vd = *(const u32x4*)(ehl + ((size_t)p * 128 + vs) * 512 + c16 * 8);
        *(u32x4*)(sm + row * 1024 + ((c16 * 16) ^ ((row & 7) << 4))) = vd;
    }
    __syncthreads();

    const __hip_bfloat16* ap0 = wxF + ((size_t)((d * 256 + jt * 8 + w * 2 + 0) * 16)) * 512;
    const __hip_bfloat16* ap1 = wxF + ((size_t)((d * 256 + jt * 8 + w * 2 + 1) * 16)) * 512;
    int hrow[2], hswz[2], lrow[2], lswz[2];
#pragma unroll
    for (int vt = 0; vt < 2; vt++) {
        int hr = vt * 16 + l15, lr = hr + 32;
        hrow[vt] = hr * 1024; hswz[vt] = (hr & 7) << 4;
        lrow[vt] = lr * 1024; lswz[vt] = (lr & 7) << 4;
    }
    f32x4 acc[2][2] = {};
#pragma unroll
    for (int kk = 0; kk < 16; kk++) {
        bf16x8 A0 = *(const bf16x8*)(ap0 + kk * 512 + lane * 8);
        bf16x8 A1 = *(const bf16x8*)(ap1 + kk * 512 + lane * 8);
        int ko = kk * 64 + l4 * 16;
        bf16x8 Bh0 = *(const bf16x8*)(sm + hrow[0] + (ko ^ hswz[0]));
        bf16x8 Bh1 = *(const bf16x8*)(sm + hrow[1] + (ko ^ hswz[1]));
        bf16x8 Bl0 = *(const bf16x8*)(sm + lrow[0] + (ko ^ lswz[0]));
        bf16x8 Bl1 = *(const bf16x8*)(sm + lrow[1] + (ko ^ lswz[1]));
        acc[0][0] = __builtin_amdgcn_mfma_f32_16x16x32_bf16(A0, Bh0, acc[0][0], 0, 0, 0);
        acc[0][0] = __builtin_amdgcn_mfma_f32_16x16x32_bf16(A0, Bl0, acc[0][0], 0, 0, 0);
        acc[0][1] = __builtin_amdgcn_mfma_f32_16x16x32_bf16(A0, Bh1, acc[0][1], 0, 0, 0);
        acc[0][1] = __builtin_amdgcn_mfma_f32_16x16x32_bf16(A0, Bl1, acc[0][1], 0, 0, 0);
        acc[1][0] = __builtin_amdgcn_mfma_f32_16x16x32_bf16(A1, Bh0, acc[1][0], 0, 0, 0);
        acc[1][0] = __builtin_amdgcn_mfma_f32_16x16x32_bf16(A1, Bl0, acc[1][0], 0, 0, 0);
        acc[1][1] = __builtin_amdgcn_mfma_f32_16x16x32_bf16(A1, Bh1, acc[1][1], 0, 0, 0);
        acc[1][1] = __builtin_amdgcn_mfma_f32_16x16x32_bf16(A1, Bl1, acc[1][1], 0, 0, 0);
    }
    const float* bp = d ? bwd_b : fwd_b;
#pragma unroll
    for (int nt = 0; nt < 2; nt++) {
        int j = jt * 32 + w * 8 + nt * 4 + l4;
        f32x4 bv = { bp[j], bp[1024 + j], bp[2048 + j], bp[3072 + j] };
#pragma unroll
        for (int vt = 0; vt < 2; vt++) {
            int v = v0 + vt * 16 + l15;
            *(f32x4*)(projP + ((size_t)(d * 1024 + j) * 128 + v) * 4) = acc[nt][vt] + bv;
        }
    }
}

// ---- fused per-step kernel: 4ngrp x 2bgrp wave tiling (halved LDS reads) ----
// block=(d, bt, jt): 64 b x 32 j (128 gate-interleaved n) — unchanged.
// wave (ngrp 0..3, bgrp 0..1): 32 n x 32 b. Per kk: 2 A (L2 stream) + 2 B (LDS)
// + 4 independent MFMA. B bank pattern = r6's free 2-way. Staging: r14
// global_load_lds with pre-swizzled source (rule #21).
__global__ __launch_bounds__(512, 1) void step_kernel(
        const int* __restrict__ x,
        const __hip_bfloat16* __restrict__ wF,
        const float* __restrict__ projP,
        __hip_bfloat16* __restrict__ hbuf,   // [2 parity][2 d][256 b][1024 j]
        float* __restrict__ cws,             // [256 blk][512 tid][4]
        int t) {
    extern __shared__ char smem[];
    const int bid = blockIdx.x;
    const int d = bid >> 7, bt = (bid >> 5) & 3, jt = bid & 31;
    const int tid = threadIdx.x, wid = tid >> 6, lane = tid & 63;
    const int ngrp = wid >> 1, bgrp = wid & 1;
    const int l15 = lane & 15, l4 = lane >> 4;
    const int b0 = bt * 64;
    const size_t dBH = (size_t)d * B * H;

    const __hip_bfloat16* wp0 = wF + (size_t)(d * 256 + jt * 8 + ngrp * 2) * 16384;
    const __hip_bfloat16* wp1 = wp0 + 16384;

    // issue first A-frags before staging (L2 latency overlaps DMA)
    bf16x8 A0c, A1c;
    if (t > 0) {
        A0c = *(const bf16x8*)(wp0 + lane * 8);
        A1c = *(const bf16x8*)(wp1 + lane * 8);
    }

    // stage h[d][b0..b0+64][0..1024] into LDS (effective XOR-swizzled layout)
    if (t > 0) {
        const char* hrb = (const char*)(hbuf + (size_t)(t & 1) * 2 * B * H + dBH + (size_t)b0 * H);
#if __has_builtin(__builtin_amdgcn_global_load_lds)
#pragma unroll
        for (int i = 0; i < 16; i++) {
            int r = i * 8 + wid;                 // 0..127 = (row, half)
            int row = r >> 1, half = r & 1;
            int m = half * 64 + lane;            // dest 16B-chunk within row
            const void* src = hrb + row * 2048 + ((m ^ (row & 7)) << 4);
            __builtin_amdgcn_global_load_lds(
                (const __attribute__((address_space(1))) void*)src,
                (__attribute__((address_space(3))) void*)(smem + row * 2048 + half * 1024),
                16, 0, 0);
        }
#else
#pragma unroll
        for (int i = 0; i < 16; i++) {
            int flat = i * 512 + tid;
            int row = flat >> 7, c16 = flat & 127;
            u32x4 v = *(const u32x4*)(hrb + (size_t)row * 2048 + c16 * 16);
            *(u32x4*)(smem + row * 2048 + ((c16 * 16) ^ ((row & 7) << 4))) = v;
        }
#endif
        __syncthreads();
    }

    f32x4 acc[2][2] = {};
    if (t > 0) {
        int brow[2], bswz[2];
#pragma unroll
        for (int bs = 0; bs < 2; bs++) {
            int row = bgrp * 32 + bs * 16 + l15;
            brow[bs] = row * 2048;
            bswz[bs] = (row & 7) << 4;
        }
        bf16x8 B0c = *(const bf16x8*)(smem + brow[0] + ((l4 * 16) ^ bswz[0]));
        bf16x8 B1c = *(const bf16x8*)(smem + brow[1] + ((l4 * 16) ^ bswz[1]));
#pragma unroll
        for (int kk = 0; kk < 32; kk++) {
            bf16x8 A0 = A0c, A1 = A1c, Bb0 = B0c, Bb1 = B1c;
            if (kk < 31) {
                A0c = *(const bf16x8*)(wp0 + (kk + 1) * 512 + lane * 8);
                A1c = *(const bf16x8*)(wp1 + (kk + 1) * 512 + lane * 8);
                int koff = (kk + 1) * 64 + l4 * 16;
                B0c = *(const bf16x8*)(smem + brow[0] + (koff ^ bswz[0]));
                B1c = *(const bf16x8*)(smem + brow[1] + (koff ^ bswz[1]));
            }
            acc[0][0] = __builtin_amdgcn_mfma_f32_16x16x32_bf16(A0, Bb0, acc[0][0], 0, 0, 0);
            acc[0][1] = __builtin_amdgcn_mfma_f32_16x16x32_bf16(A0, Bb1, acc[0][1], 0, 0, 0);
            acc[1][0] = __builtin_amdgcn_mfma_f32_16x16x32_bf16(A1, Bb0, acc[1][0], 0, 0, 0);
            acc[1][1] = __builtin_amdgcn_mfma_f32_16x16x32_bf16(A1, Bb1, acc[1][1], 0, 0, 0);
        }
    }

    // proj gather: lane owns (j = jt*32 + ngrp*8 + frag*4 + l4, b = b0 + bgrp*32 + bs*16 + l15)
    const int tt = d ? (S - 1 - t) : t;
    int vv[2];
#pragma unroll
    for (int bs = 0; bs < 2; bs++)
        vv[bs] = x[(b0 + bgrp * 32 + bs * 16 + l15) * S + tt];
    f32x4 pj[2][2];
#pragma unroll
    for (int frag = 0; frag < 2; frag++) {
        int j = jt * 32 + ngrp * 8 + frag * 4 + l4;
        const f32x4* pp = (const f32x4*)projP + ((size_t)d * 1024 + j) * 128;
#pragma unroll
        for (int bs = 0; bs < 2; bs++) pj[frag][bs] = pp[vv[bs]];
    }

    float* cp = cws + ((size_t)bid * 512 + tid) * 4;
    f32x4 cv = {0.f, 0.f, 0.f, 0.f};
    if (t > 0) cv = *(const f32x4*)cp;

    // gates: acc[frag][bs][reg] = gate reg of (j(frag), b(bs))
    float hnv[2][2];
#pragma unroll
    for (int frag = 0; frag < 2; frag++)
#pragma unroll
        for (int bs = 0; bs < 2; bs++) {
            float zg = acc[frag][bs][0] + pj[frag][bs][0];
            float zi = acc[frag][bs][1] + pj[frag][bs][1];
            float zf = acc[frag][bs][2] + pj[frag][bs][2];
            float zo = acc[frag][bs][3] + pj[frag][bs][3];
            float gg = tanh_fast(zg);
            float ii = sigf(zi);
            float ff = sigf(zf);
            float oo = sigf(zo);
            int ci = frag * 2 + bs;
            float cn = gg * ii + cv[ci] * ff;
            cv[ci] = cn;
            hnv[frag][bs] = tanh_fast(cn) * oo;
        }
    *(f32x4*)cp = cv;

    // register shfl transpose: lane L stores b = bgrp*32 + (L&31), j-half = L>>5.
    // source of h(j = base + (L>>5)*4 + p, b): lane p*16 + (L&15), frag = L>>5,
    // bs = (L>>4)&1.
    unsigned wA = (unsigned)f2bf(hnv[0][0]) | ((unsigned)f2bf(hnv[0][1]) << 16);
    unsigned wB = (unsigned)f2bf(hnv[1][0]) | ((unsigned)f2bf(hnv[1][1]) << 16);
    unsigned short o4[4];
#pragma unroll
    for (int p = 0; p < 4; p++) {
        int src = p * 16 + l15;
        unsigned va = __shfl(wA, src);
        unsigned vb = __shfl(wB, src);
        unsigned sel = (lane >= 32) ? vb : va;
        o4[p] = ((lane >> 4) & 1) ? (unsigned short)(sel >> 16)
                                  : (unsigned short)(sel & 0xffffu);
    }
    u64 hv = (u64)o4[0] | ((u64)o4[1] << 16) | ((u64)o4[2] << 32) | ((u64)o4[3] << 48);
    __hip_bfloat16* hw = hbuf + (size_t)((t + 1) & 1) * 2 * B * H + dBH
                         + (size_t)(b0 + bgrp * 32 + (lane & 31)) * H
                         + jt * 32 + ngrp * 8 + (lane >> 5) * 4;
    *(u64a*)hw = hv;
}

// ---- head: logits + log_softmax (reads bf16 h, parity 0) ----
__global__ void head_kernel(const __hip_bfloat16* __restrict__ hbuf,
                            const float* __restrict__ p_w,
                            const float* __restrict__ p_b,
                            float* __restrict__ out) {
    int b = blockIdx.x;
    int lane = threadIdx.x;  // 64
    float part[C];
#pragma unroll
    for (int cc = 0; cc < C; cc++) part[cc] = 0.0f;
    for (int jj = lane; jj < 2 * H; jj += 64) {
        float hv = (jj < H)
            ? __bfloat162float(hbuf[(size_t)b * H + jj])
            : __bfloat162float(hbuf[(size_t)B * H + (size_t)b * H + jj - H]);
#pragma unroll
        for (int cc = 0; cc < C; cc++) part[cc] += hv * p_w[cc * 2 * H + jj];
    }
#pragma unroll
    for (int cc = 0; cc < C; cc++) {
        float v = part[cc];
        for (int off = 32; off; off >>= 1) v += __shfl_down(v, off);
        part[cc] = v;
    }
    if (lane == 0) {
        float lg[C];
        float m = -1e30f;
        for (int cc = 0; cc < C; cc++) {
            lg[cc] = part[cc] + p_b[cc];
            m = fmaxf(m, lg[cc]);
        }
        float s = 0.0f;
        for (int cc = 0; cc < C; cc++) s += expf(lg[cc] - m);
        float lse = logf(s) + m;
        for (int cc = 0; cc < C; cc++) out[b * C + cc] = lg[cc] - lse;
    }
}

extern "C" void kernel_launch(void* const* d_in, const int* in_sizes, int n_in,
                              void* d_out, int out_size, void* d_ws, size_t ws_size,
                              hipStream_t stream) {
    const int*   x     = (const int*)d_in[0];
    const float* embed = (const float*)d_in[1];
    const float* fwd_W = (const float*)d_in[2];
    const float* fwd_b = (const float*)d_in[3];
    const float* bwd_W = (const float*)d_in[4];
    const float* bwd_b = (const float*)d_in[5];
    const float* p_w   = (const float*)d_in[6];
    const float* p_b   = (const float*)d_in[7];
    float* outp = (float*)d_out;

    char* ws = (char*)d_ws;
    __hip_bfloat16* wF  = (__hip_bfloat16*)ws;  ws += (size_t)2 * 256 * 16384 * 2;    // 16 MB
    // 8 MB region shared in time: wxF (prep only) overlays cws (steps only)
    __hip_bfloat16* wxF = (__hip_bfloat16*)ws;
    float* cws = (float*)ws;                    ws += (size_t)2 * 256 * 8192 * 2;     // 8 MB
    unsigned short* ehl = (unsigned short*)ws;  ws += (size_t)2 * 128 * 512 * 2;      // 256 KB
    float* projP = (float*)ws;                  ws += (size_t)2 * 1024 * 128 * 4 * 4; // 4 MB
    __hip_bfloat16* hbuf = (__hip_bfloat16*)ws; ws += (size_t)2 * 2 * B * H * 2;      // 2 MB

    hipLaunchKernelGGL(prep_build, dim3(6400), dim3(256), 0, stream,
                       fwd_W, bwd_W, embed, wF, wxF, ehl);

    hipFuncSetAttribute((const void*)projp_mfma,
                        hipFuncAttributeMaxDynamicSharedMemorySize, 65536);
    hipLaunchKernelGGL(projp_mfma, dim3(256), dim3(256), 65536, stream,
                       wxF, ehl, fwd_b, bwd_b, projP);

    hipFuncSetAttribute((const void*)step_kernel,
                        hipFuncAttributeMaxDynamicSharedMemorySize, LDS_H);
    for (int t = 0; t < S; t++)
        hipLaunchKernelGGL(step_kernel, dim3(256), dim3(512), LDS_H, stream,
                           x, wF, projP, hbuf, cws, t);

    hipLaunchKernelGGL(head_kernel, dim3(B), dim3(64), 0, stream,
                       hbuf, p_w, p_b, outp);
}

// Round 16
// 1442.842 us; speedup vs baseline: 1.1500x; 1.1500x over previous
//
#include <hip/hip_runtime.h>
#include <hip/hip_bf16.h>
#include <math.h>

#define B 256
#define S 128
#define I_DIM 512
#define H 1024
#define C 10
#define WROW 1536

#define LDS_H 131072                 // 64 b-rows x 1024 k bf16, XOR-swizzled

typedef float f32x4 __attribute__((ext_vector_type(4), may_alias));
typedef __bf16 bf16x8 __attribute__((ext_vector_type(8), may_alias));
typedef unsigned int u32x4 __attribute__((ext_vector_type(4), may_alias));
typedef unsigned long long u64;
typedef unsigned long long __attribute__((may_alias)) u64a;

__device__ __forceinline__ unsigned short f2bf(float f) {
    union { float f; unsigned u; } a; a.f = f;
    return (unsigned short)((a.u + 0x7fffu + ((a.u >> 16) & 1u)) >> 16);
}
__device__ __forceinline__ float bf2f(unsigned short b) {
    union { unsigned u; float f; } a; a.u = ((unsigned)b) << 16;
    return a.f;
}
__device__ __forceinline__ float sigf(float v) { return 1.0f / (1.0f + __expf(-v)); }
__device__ __forceinline__ float tanh_fast(float v) { return 1.0f - 2.0f / (1.0f + __expf(2.0f * v)); }

// ---- fused prep: wF + wxF + ehl (verified r14) ----
__global__ void prep_build(const float* __restrict__ fwd_W,
                           const float* __restrict__ bwd_W,
                           const float* __restrict__ embed,
                           __hip_bfloat16* __restrict__ wF,
                           __hip_bfloat16* __restrict__ wxF,
                           unsigned short* __restrict__ ehl) {
    int gid = blockIdx.x * 256 + threadIdx.x;
    if (gid < 1048576) {
        int lane = gid & 63, kk = (gid >> 6) & 31, nsub = (gid >> 11) & 255, d = gid >> 19;
        int n_gl = nsub * 16 + (lane & 15);
        int j = n_gl >> 2, g = n_gl & 3;
        int k = kk * 32 + (lane >> 4) * 8;
        const float* W = d ? bwd_W : fwd_W;
        const float* src = W + (size_t)(g * 1024 + j) * WROW + I_DIM + k;
        ushort4 lo = make_ushort4(f2bf(src[0]), f2bf(src[1]), f2bf(src[2]), f2bf(src[3]));
        ushort4 hi = make_ushort4(f2bf(src[4]), f2bf(src[5]), f2bf(src[6]), f2bf(src[7]));
        ushort4* dst = (ushort4*)(wF + (size_t)gid * 8);
        dst[0] = lo; dst[1] = hi;
    } else if (gid < 1048576 + 524288) {
        int g2 = gid - 1048576;
        int lane = g2 & 63, kk = (g2 >> 6) & 15, nsub = (g2 >> 10) & 255, d = g2 >> 18;
        int n_gl = nsub * 16 + (lane & 15);
        int j = n_gl >> 2, g = n_gl & 3;
        int k = kk * 32 + (lane >> 4) * 8;
        const float* W = d ? bwd_W : fwd_W;
        const float* src = W + (size_t)(g * 1024 + j) * WROW + k;
        ushort4 lo = make_ushort4(f2bf(src[0]), f2bf(src[1]), f2bf(src[2]), f2bf(src[3]));
        ushort4 hi = make_ushort4(f2bf(src[4]), f2bf(src[5]), f2bf(src[6]), f2bf(src[7]));
        ushort4* dst = (ushort4*)(wxF + (size_t)g2 * 8);
        dst[0] = lo; dst[1] = hi;
    } else {
        int idx = gid - (1048576 + 524288);   // 0..65535
        float e = embed[idx];
        unsigned short hb = f2bf(e);
        unsigned short lb = f2bf(e - bf2f(hb));
        ehl[idx] = hb;
        ehl[65536 + idx] = lb;
    }
}

// ---- prep 2: projP[d][j][v][g] via split-bf16 MFMA (verified r10-r15) ----
__global__ __launch_bounds__(256) void projp_mfma(
        const __hip_bfloat16* __restrict__ wxF,
        const unsigned short* __restrict__ ehl,
        const float* __restrict__ fwd_b,
        const float* __restrict__ bwd_b,
        float* __restrict__ projP) {
    extern __shared__ char sm[];
    const int bid = blockIdx.x;
    const int d = bid >> 7, jt = (bid >> 2) & 31, vb = bid & 3;
    const int tid = threadIdx.x, w = tid >> 6, lane = tid & 63;
    const int l15 = lane & 15, l4 = lane >> 4;
    const int v0 = vb * 32;

    for (int i = 0; i < 16; i++) {
        int chunk = i * 256 + tid;
        int row = chunk >> 6, c16 = chunk & 63;
        int p = row >> 5, vs = v0 + (row & 31);
        u32x4 vd = *(const u32x4*)(ehl + ((size_t)p * 128 + vs) * 512 + c16 * 8);
        *(u32x4*)(sm + row * 1024 + ((c16 * 16) ^ ((row & 7) << 4))) = vd;
    }
    __syncthreads();

    const __hip_bfloat16* ap0 = wxF + ((size_t)((d * 256 + jt * 8 + w * 2 + 0) * 16)) * 512;
    const __hip_bfloat16* ap1 = wxF + ((size_t)((d * 256 + jt * 8 + w * 2 + 1) * 16)) * 512;
    int hrow[2], hswz[2], lrow[2], lswz[2];
#pragma unroll
    for (int vt = 0; vt < 2; vt++) {
        int hr = vt * 16 + l15, lr = hr + 32;
        hrow[vt] = hr * 1024; hswz[vt] = (hr & 7) << 4;
        lrow[vt] = lr * 1024; lswz[vt] = (lr & 7) << 4;
    }
    f32x4 acc[2][2] = {};
#pragma unroll
    for (int kk = 0; kk < 16; kk++) {
        bf16x8 A0 = *(const bf16x8*)(ap0 + kk * 512 + lane * 8);
        bf16x8 A1 = *(const bf16x8*)(ap1 + kk * 512 + lane * 8);
        int ko = kk * 64 + l4 * 16;
        bf16x8 Bh0 = *(const bf16x8*)(sm + hrow[0] + (ko ^ hswz[0]));
        bf16x8 Bh1 = *(const bf16x8*)(sm + hrow[1] + (ko ^ hswz[1]));
        bf16x8 Bl0 = *(const bf16x8*)(sm + lrow[0] + (ko ^ lswz[0]));
        bf16x8 Bl1 = *(const bf16x8*)(sm + lrow[1] + (ko ^ lswz[1]));
        acc[0][0] = __builtin_amdgcn_mfma_f32_16x16x32_bf16(A0, Bh0, acc[0][0], 0, 0, 0);
        acc[0][0] = __builtin_amdgcn_mfma_f32_16x16x32_bf16(A0, Bl0, acc[0][0], 0, 0, 0);
        acc[0][1] = __builtin_amdgcn_mfma_f32_16x16x32_bf16(A0, Bh1, acc[0][1], 0, 0, 0);
        acc[0][1] = __builtin_amdgcn_mfma_f32_16x16x32_bf16(A0, Bl1, acc[0][1], 0, 0, 0);
        acc[1][0] = __builtin_amdgcn_mfma_f32_16x16x32_bf16(A1, Bh0, acc[1][0], 0, 0, 0);
        acc[1][0] = __builtin_amdgcn_mfma_f32_16x16x32_bf16(A1, Bl0, acc[1][0], 0, 0, 0);
        acc[1][1] = __builtin_amdgcn_mfma_f32_16x16x32_bf16(A1, Bh1, acc[1][1], 0, 0, 0);
        acc[1][1] = __builtin_amdgcn_mfma_f32_16x16x32_bf16(A1, Bl1, acc[1][1], 0, 0, 0);
    }
    const float* bp = d ? bwd_b : fwd_b;
#pragma unroll
    for (int nt = 0; nt < 2; nt++) {
        int j = jt * 32 + w * 8 + nt * 4 + l4;
        f32x4 bv = { bp[j], bp[1024 + j], bp[2048 + j], bp[3072 + j] };
#pragma unroll
        for (int vt = 0; vt < 2; vt++) {
            int v = v0 + vt * 16 + l15;
            *(f32x4*)(projP + ((size_t)(d * 1024 + j) * 128 + v) * 4) = acc[nt][vt] + bv;
        }
    }
}

// ---- fused per-step kernel: r14 structure + issue-reordered gathers ----
// block=(d, bt, jt): 64 b x 32 j (128 gate-interleaved n). 8 waves of 16n x 64b.
// Staging via global_load_lds with pre-swizzled source (r14, verified).
// x/pj/cv/first-A issued BEFORE the barrier so latency hides under the DMA.
__global__ __launch_bounds__(512, 1) void step_kernel(
        const int* __restrict__ x,
        const __hip_bfloat16* __restrict__ wF,
        const float* __restrict__ projP,
        __hip_bfloat16* __restrict__ hbuf,   // [2 parity][2 d][256 b][1024 j]
        float* __restrict__ cws,             // [256 blk][512 tid][4]
        int t) {
    extern __shared__ char smem[];
    const int bid = blockIdx.x;
    const int d = bid >> 7, bt = (bid >> 5) & 3, jt = bid & 31;
    const int tid = threadIdx.x, wid = tid >> 6, lane = tid & 63;
    const int l15 = lane & 15, l4 = lane >> 4;
    const int b0 = bt * 64;
    const size_t dBH = (size_t)d * B * H;

    // issue x gather first (independent of everything)
    const int tt = d ? (S - 1 - t) : t;
    int vv[4];
#pragma unroll
    for (int bs = 0; bs < 4; bs++)
        vv[bs] = x[(b0 + bs * 16 + l15) * S + tt];

    // stage h[d][b0..b0+64][0..1024] into LDS (effective XOR-swizzled layout)
    if (t > 0) {
        const char* hrb = (const char*)(hbuf + (size_t)(t & 1) * 2 * B * H + dBH + (size_t)b0 * H);
#if __has_builtin(__builtin_amdgcn_global_load_lds)
#pragma unroll
        for (int i = 0; i < 16; i++) {
            int r = i * 8 + wid;                 // 0..127 = (row, half)
            int row = r >> 1, half = r & 1;
            int m = half * 64 + lane;            // dest 16B-chunk within row
            const void* src = hrb + row * 2048 + ((m ^ (row & 7)) << 4);
            __builtin_amdgcn_global_load_lds(
                (const __attribute__((address_space(1))) void*)src,
                (__attribute__((address_space(3))) void*)(smem + row * 2048 + half * 1024),
                16, 0, 0);
        }
#else
#pragma unroll
        for (int i = 0; i < 16; i++) {
            int flat = i * 512 + tid;
            int row = flat >> 7, c16 = flat & 127;
            u32x4 v = *(const u32x4*)(hrb + (size_t)row * 2048 + c16 * 16);
            *(u32x4*)(smem + row * 2048 + ((c16 * 16) ^ ((row & 7) << 4))) = v;
        }
#endif
    }

    // pj / cv / first A-frag: issue while the DMA drains (before the barrier)
    const int j = jt * 32 + wid * 4 + l4;
    const f32x4* pp = (const f32x4*)projP + ((size_t)d * 1024 + j) * 128;
    f32x4 pj[4];
#pragma unroll
    for (int bs = 0; bs < 4; bs++) pj[bs] = pp[vv[bs]];

    float* cp = cws + ((size_t)bid * 512 + tid) * 4;
    f32x4 cv = {0.f, 0.f, 0.f, 0.f};
    if (t > 0) cv = *(const f32x4*)cp;

    const __hip_bfloat16* wp = wF + (size_t)(d * 256 + jt * 8 + wid) * 16384;
    bf16x8 Acur;
    if (t > 0) Acur = *(const bf16x8*)(wp + lane * 8);

    f32x4 acc[4] = {};
    if (t > 0) {
        __syncthreads();
        int brow[4], bswz[4];
#pragma unroll
        for (int bs = 0; bs < 4; bs++) {
            int row = bs * 16 + l15;
            brow[bs] = row * 2048;
            bswz[bs] = (row & 7) << 4;
        }
        bf16x8 Bcur[4];
#pragma unroll
        for (int bs = 0; bs < 4; bs++)
            Bcur[bs] = *(const bf16x8*)(smem + brow[bs] + ((l4 * 16) ^ bswz[bs]));
#pragma unroll
        for (int kk = 0; kk < 32; kk++) {
            bf16x8 A = Acur;
            bf16x8 B0 = Bcur[0], B1 = Bcur[1], B2 = Bcur[2], B3 = Bcur[3];
            if (kk < 31) {
                Acur = *(const bf16x8*)(wp + (kk + 1) * 512 + lane * 8);
                int koff = (kk + 1) * 64 + l4 * 16;
#pragma unroll
                for (int bs = 0; bs < 4; bs++)
                    Bcur[bs] = *(const bf16x8*)(smem + brow[bs] + (koff ^ bswz[bs]));
            }
            acc[0] = __builtin_amdgcn_mfma_f32_16x16x32_bf16(A, B0, acc[0], 0, 0, 0);
            acc[1] = __builtin_amdgcn_mfma_f32_16x16x32_bf16(A, B1, acc[1], 0, 0, 0);
            acc[2] = __builtin_amdgcn_mfma_f32_16x16x32_bf16(A, B2, acc[2], 0, 0, 0);
            acc[3] = __builtin_amdgcn_mfma_f32_16x16x32_bf16(A, B3, acc[3], 0, 0, 0);
        }
    }

    float hnv[4];
#pragma unroll
    for (int bs = 0; bs < 4; bs++) {
        float zg = acc[bs][0] + pj[bs][0];
        float zi = acc[bs][1] + pj[bs][1];
        float zf = acc[bs][2] + pj[bs][2];
        float zo = acc[bs][3] + pj[bs][3];
        float gg = tanh_fast(zg);
        float ii = sigf(zi);
        float ff = sigf(zf);
        float oo = sigf(zo);
        float cn = gg * ii + cv[bs] * ff;
        cv[bs] = cn;
        hnv[bs] = tanh_fast(cn) * oo;
    }
    *(f32x4*)cp = cv;

    // pure-register wave transpose via shfl (verified r6-r14 pattern)
    unsigned plo = (unsigned)f2bf(hnv[0]) | ((unsigned)f2bf(hnv[1]) << 16);
    unsigned phi = (unsigned)f2bf(hnv[2]) | ((unsigned)f2bf(hnv[3]) << 16);
    unsigned short o4[4];
#pragma unroll
    for (int p = 0; p < 4; p++) {
        int src = p * 16 + l15;
        unsigned vlo = __shfl(plo, src);
        unsigned vhi = __shfl(phi, src);
        unsigned sel = (l4 < 2) ? vlo : vhi;
        o4[p] = (l4 & 1) ? (unsigned short)(sel >> 16) : (unsigned short)(sel & 0xffffu);
    }
    u64 hv = (u64)o4[0] | ((u64)o4[1] << 16) | ((u64)o4[2] << 32) | ((u64)o4[3] << 48);
    __hip_bfloat16* hw = hbuf + (size_t)((t + 1) & 1) * 2 * B * H + dBH
                         + (size_t)(b0 + lane) * H + jt * 32 + wid * 4;
    *(u64a*)hw = hv;
}

// ---- head: logits + log_softmax (reads bf16 h, parity 0) ----
__global__ void head_kernel(const __hip_bfloat16* __restrict__ hbuf,
                            const float* __restrict__ p_w,
                            const float* __restrict__ p_b,
                            float* __restrict__ out) {
    int b = blockIdx.x;
    int lane = threadIdx.x;  // 64
    float part[C];
#pragma unroll
    for (int cc = 0; cc < C; cc++) part[cc] = 0.0f;
    for (int jj = lane; jj < 2 * H; jj += 64) {
        float hv = (jj < H)
            ? __bfloat162float(hbuf[(size_t)b * H + jj])
            : __bfloat162float(hbuf[(size_t)B * H + (size_t)b * H + jj - H]);
#pragma unroll
        for (int cc = 0; cc < C; cc++) part[cc] += hv * p_w[cc * 2 * H + jj];
    }
#pragma unroll
    for (int cc = 0; cc < C; cc++) {
        float v = part[cc];
        for (int off = 32; off; off >>= 1) v += __shfl_down(v, off);
        part[cc] = v;
    }
    if (lane == 0) {
        float lg[C];
        float m = -1e30f;
        for (int cc = 0; cc < C; cc++) {
            lg[cc] = part[cc] + p_b[cc];
            m = fmaxf(m, lg[cc]);
        }
        float s = 0.0f;
        for (int cc = 0; cc < C; cc++) s += expf(lg[cc] - m);
        float lse = logf(s) + m;
        for (int cc = 0; cc < C; cc++) out[b * C + cc] = lg[cc] - lse;
    }
}

extern "C" void kernel_launch(void* const* d_in, const int* in_sizes, int n_in,
                              void* d_out, int out_size, void* d_ws, size_t ws_size,
                              hipStream_t stream) {
    const int*   x     = (const int*)d_in[0];
    const float* embed = (const float*)d_in[1];
    const float* fwd_W = (const float*)d_in[2];
    const float* fwd_b = (const float*)d_in[3];
    const float* bwd_W = (const float*)d_in[4];
    const float* bwd_b = (const float*)d_in[5];
    const float* p_w   = (const float*)d_in[6];
    const float* p_b   = (const float*)d_in[7];
    float* outp = (float*)d_out;

    char* ws = (char*)d_ws;
    __hip_bfloat16* wF  = (__hip_bfloat16*)ws;  ws += (size_t)2 * 256 * 16384 * 2;    // 16 MB
    // 8 MB region shared in time: wxF (prep only) overlays cws (steps only)
    __hip_bfloat16* wxF = (__hip_bfloat16*)ws;
    float* cws = (float*)ws;                    ws += (size_t)2 * 256 * 8192 * 2;     // 8 MB
    unsigned short* ehl = (unsigned short*)ws;  ws += (size_t)2 * 128 * 512 * 2;      // 256 KB
    float* projP = (float*)ws;                  ws += (size_t)2 * 1024 * 128 * 4 * 4; // 4 MB
    __hip_bfloat16* hbuf = (__hip_bfloat16*)ws; ws += (size_t)2 * 2 * B * H * 2;      // 2 MB

    hipLaunchKernelGGL(prep_build, dim3(6400), dim3(256), 0, stream,
                       fwd_W, bwd_W, embed, wF, wxF, ehl);

    hipFuncSetAttribute((const void*)projp_mfma,
                        hipFuncAttributeMaxDynamicSharedMemorySize, 65536);
    hipLaunchKernelGGL(projp_mfma, dim3(256), dim3(256), 65536, stream,
                       wxF, ehl, fwd_b, bwd_b, projP);

    hipFuncSetAttribute((const void*)step_kernel,
                        hipFuncAttributeMaxDynamicSharedMemorySize, LDS_H);
    for (int t = 0; t < S; t++)
        hipLaunchKernelGGL(step_kernel, dim3(256), dim3(512), LDS_H, stream,
                           x, wF, projP, hbuf, cws, t);

    hipLaunchKernelGGL(head_kernel, dim3(B), dim3(64), 0, stream,
                       hbuf, p_w, p_b, outp);
}

// Round 17
// 1413.594 us; speedup vs baseline: 1.1738x; 1.0207x over previous
//
#include <hip/hip_runtime.h>
#include <hip/hip_bf16.h>
#include <math.h>

#define B 256
#define S 128
#define I_DIM 512
#define H 1024
#define C 10
#define WROW 1536

#define LDS_H 131072                 // 64 b-rows x 1024 k bf16, XOR-swizzled

typedef float f32x4 __attribute__((ext_vector_type(4), may_alias));
typedef __bf16 bf16x8 __attribute__((ext_vector_type(8), may_alias));
typedef unsigned int u32x4 __attribute__((ext_vector_type(4), may_alias));
typedef unsigned long long u64;
typedef unsigned long long __attribute__((may_alias)) u64a;

__device__ __forceinline__ unsigned short f2bf(float f) {
    union { float f; unsigned u; } a; a.f = f;
    return (unsigned short)((a.u + 0x7fffu + ((a.u >> 16) & 1u)) >> 16);
}
__device__ __forceinline__ float bf2f(unsigned short b) {
    union { unsigned u; float f; } a; a.u = ((unsigned)b) << 16;
    return a.f;
}
__device__ __forceinline__ float sigf(float v) { return 1.0f / (1.0f + __expf(-v)); }
__device__ __forceinline__ float tanh_fast(float v) { return 1.0f - 2.0f / (1.0f + __expf(2.0f * v)); }

// ---- fused prep: wF (recurrent frag stream) + wxF (input-proj frag stream)
//      + ehl (split-bf16 embed). One kernel, 3 gid regions. ----
__global__ void prep_build(const float* __restrict__ fwd_W,
                           const float* __restrict__ bwd_W,
                           const float* __restrict__ embed,
                           __hip_bfloat16* __restrict__ wF,
                           __hip_bfloat16* __restrict__ wxF,
                           unsigned short* __restrict__ ehl) {
    int gid = blockIdx.x * 256 + threadIdx.x;
    if (gid < 1048576) {
        // wF[(((d*256+nsub)*32+kk)*64+lane)*8+e] = W_d[g*1024+j][512+kk*32+(lane>>4)*8+e]
        int lane = gid & 63, kk = (gid >> 6) & 31, nsub = (gid >> 11) & 255, d = gid >> 19;
        int n_gl = nsub * 16 + (lane & 15);
        int j = n_gl >> 2, g = n_gl & 3;
        int k = kk * 32 + (lane >> 4) * 8;
        const float* W = d ? bwd_W : fwd_W;
        const float* src = W + (size_t)(g * 1024 + j) * WROW + I_DIM + k;
        ushort4 lo = make_ushort4(f2bf(src[0]), f2bf(src[1]), f2bf(src[2]), f2bf(src[3]));
        ushort4 hi = make_ushort4(f2bf(src[4]), f2bf(src[5]), f2bf(src[6]), f2bf(src[7]));
        ushort4* dst = (ushort4*)(wF + (size_t)gid * 8);
        dst[0] = lo; dst[1] = hi;
    } else if (gid < 1048576 + 524288) {
        int g2 = gid - 1048576;
        int lane = g2 & 63, kk = (g2 >> 6) & 15, nsub = (g2 >> 10) & 255, d = g2 >> 18;
        int n_gl = nsub * 16 + (lane & 15);
        int j = n_gl >> 2, g = n_gl & 3;
        int k = kk * 32 + (lane >> 4) * 8;
        const float* W = d ? bwd_W : fwd_W;
        const float* src = W + (size_t)(g * 1024 + j) * WROW + k;
        ushort4 lo = make_ushort4(f2bf(src[0]), f2bf(src[1]), f2bf(src[2]), f2bf(src[3]));
        ushort4 hi = make_ushort4(f2bf(src[4]), f2bf(src[5]), f2bf(src[6]), f2bf(src[7]));
        ushort4* dst = (ushort4*)(wxF + (size_t)g2 * 8);
        dst[0] = lo; dst[1] = hi;
    } else {
        int idx = gid - (1048576 + 524288);   // 0..65535
        float e = embed[idx];
        unsigned short hb = f2bf(e);
        unsigned short lb = f2bf(e - bf2f(hb));
        ehl[idx] = hb;
        ehl[65536 + idx] = lb;
    }
}

// ---- prep 2: projP[d][j][v][g] via split-bf16 MFMA (verified r10-r16) ----
__global__ __launch_bounds__(256) void projp_mfma(
        const __hip_bfloat16* __restrict__ wxF,
        const unsigned short* __restrict__ ehl,
        const float* __restrict__ fwd_b,
        const float* __restrict__ bwd_b,
        float* __restrict__ projP) {
    extern __shared__ char sm[];
    const int bid = blockIdx.x;
    const int d = bid >> 7, jt = (bid >> 2) & 31, vb = bid & 3;
    const int tid = threadIdx.x, w = tid >> 6, lane = tid & 63;
    const int l15 = lane & 15, l4 = lane >> 4;
    const int v0 = vb * 32;

    for (int i = 0; i < 16; i++) {
        int chunk = i * 256 + tid;
        int row = chunk >> 6, c16 = chunk & 63;
        int p = row >> 5, vs = v0 + (row & 31);
        u32x4 vd = *(const u32x4*)(ehl + ((size_t)p * 128 + vs) * 512 + c16 * 8);
        *(u32x4*)(sm + row * 1024 + ((c16 * 16) ^ ((row & 7) << 4))) = vd;
    }
    __syncthreads();

    const __hip_bfloat16* ap0 = wxF + ((size_t)((d * 256 + jt * 8 + w * 2 + 0) * 16)) * 512;
    const __hip_bfloat16* ap1 = wxF + ((size_t)((d * 256 + jt * 8 + w * 2 + 1) * 16)) * 512;
    int hrow[2], hswz[2], lrow[2], lswz[2];
#pragma unroll
    for (int vt = 0; vt < 2; vt++) {
        int hr = vt * 16 + l15, lr = hr + 32;
        hrow[vt] = hr * 1024; hswz[vt] = (hr & 7) << 4;
        lrow[vt] = lr * 1024; lswz[vt] = (lr & 7) << 4;
    }
    f32x4 acc[2][2] = {};
#pragma unroll
    for (int kk = 0; kk < 16; kk++) {
        bf16x8 A0 = *(const bf16x8*)(ap0 + kk * 512 + lane * 8);
        bf16x8 A1 = *(const bf16x8*)(ap1 + kk * 512 + lane * 8);
        int ko = kk * 64 + l4 * 16;
        bf16x8 Bh0 = *(const bf16x8*)(sm + hrow[0] + (ko ^ hswz[0]));
        bf16x8 Bh1 = *(const bf16x8*)(sm + hrow[1] + (ko ^ hswz[1]));
        bf16x8 Bl0 = *(const bf16x8*)(sm + lrow[0] + (ko ^ lswz[0]));
        bf16x8 Bl1 = *(const bf16x8*)(sm + lrow[1] + (ko ^ lswz[1]));
        acc[0][0] = __builtin_amdgcn_mfma_f32_16x16x32_bf16(A0, Bh0, acc[0][0], 0, 0, 0);
        acc[0][0] = __builtin_amdgcn_mfma_f32_16x16x32_bf16(A0, Bl0, acc[0][0], 0, 0, 0);
        acc[0][1] = __builtin_amdgcn_mfma_f32_16x16x32_bf16(A0, Bh1, acc[0][1], 0, 0, 0);
        acc[0][1] = __builtin_amdgcn_mfma_f32_16x16x32_bf16(A0, Bl1, acc[0][1], 0, 0, 0);
        acc[1][0] = __builtin_amdgcn_mfma_f32_16x16x32_bf16(A1, Bh0, acc[1][0], 0, 0, 0);
        acc[1][0] = __builtin_amdgcn_mfma_f32_16x16x32_bf16(A1, Bl0, acc[1][0], 0, 0, 0);
        acc[1][1] = __builtin_amdgcn_mfma_f32_16x16x32_bf16(A1, Bh1, acc[1][1], 0, 0, 0);
        acc[1][1] = __builtin_amdgcn_mfma_f32_16x16x32_bf16(A1, Bl1, acc[1][1], 0, 0, 0);
    }
    const float* bp = d ? bwd_b : fwd_b;
#pragma unroll
    for (int nt = 0; nt < 2; nt++) {
        int j = jt * 32 + w * 8 + nt * 4 + l4;
        f32x4 bv = { bp[j], bp[1024 + j], bp[2048 + j], bp[3072 + j] };
#pragma unroll
        for (int vt = 0; vt < 2; vt++) {
            int v = v0 + vt * 16 + l15;
            *(f32x4*)(projP + ((size_t)(d * 1024 + j) * 128 + v) * 4) = acc[nt][vt] + bv;
        }
    }
}

// ---- fused per-step kernel: r6 GEMM/gates verbatim; staging via global_load_lds ----
// LDS layout identical to r6: LDS[row][m] = global[row][m ^ (row&7)] (16B chunks).
// global_load_lds writes linear (wave-uniform base + lane*16), so the source
// address is pre-swizzled per lane (rule #21 / m173 pattern).
// Best-measured version (r14: 1415 us total, 10.7 us/step).
__global__ __launch_bounds__(512, 1) void step_kernel(
        const int* __restrict__ x,
        const __hip_bfloat16* __restrict__ wF,
        const float* __restrict__ projP,
        __hip_bfloat16* __restrict__ hbuf,   // [2 parity][2 d][256 b][1024 j]
        float* __restrict__ cws,             // [256 blk][512 tid][4]
        int t) {
    extern __shared__ char smem[];
    const int bid = blockIdx.x;
    const int d = bid >> 7, bt = (bid >> 5) & 3, jt = bid & 31;
    const int tid = threadIdx.x, wid = tid >> 6, lane = tid & 63;
    const int l15 = lane & 15, l4 = lane >> 4;
    const int b0 = bt * 64;
    const size_t dBH = (size_t)d * B * H;

    // stage h[d][b0..b0+64][0..1024] into LDS (effective XOR-swizzled layout)
    if (t > 0) {
        const char* hrb = (const char*)(hbuf + (size_t)(t & 1) * 2 * B * H + dBH + (size_t)b0 * H);
#if __has_builtin(__builtin_amdgcn_global_load_lds)
#pragma unroll
        for (int i = 0; i < 16; i++) {
            int r = i * 8 + wid;                 // 0..127 = (row, half)
            int row = r >> 1, half = r & 1;
            int m = half * 64 + lane;            // dest 16B-chunk within row
            const void* src = hrb + row * 2048 + ((m ^ (row & 7)) << 4);
            __builtin_amdgcn_global_load_lds(
                (const __attribute__((address_space(1))) void*)src,
                (__attribute__((address_space(3))) void*)(smem + row * 2048 + half * 1024),
                16, 0, 0);
        }
#else
#pragma unroll
        for (int i = 0; i < 16; i++) {
            int flat = i * 512 + tid;
            int row = flat >> 7, c16 = flat & 127;
            u32x4 v = *(const u32x4*)(hrb + (size_t)row * 2048 + c16 * 16);
            *(u32x4*)(smem + row * 2048 + ((c16 * 16) ^ ((row & 7) << 4))) = v;
        }
#endif
        __syncthreads();
    }

    f32x4 acc[4] = {};
    if (t > 0) {
        const __hip_bfloat16* wp = wF + (size_t)(d * 256 + jt * 8 + wid) * 16384;
        int brow[4], bswz[4];
#pragma unroll
        for (int bs = 0; bs < 4; bs++) {
            int row = bs * 16 + l15;
            brow[bs] = row * 2048;
            bswz[bs] = (row & 7) << 4;
        }
        bf16x8 Acur = *(const bf16x8*)(wp + lane * 8);
        bf16x8 Bcur[4];
#pragma unroll
        for (int bs = 0; bs < 4; bs++)
            Bcur[bs] = *(const bf16x8*)(smem + brow[bs] + ((l4 * 16) ^ bswz[bs]));
#pragma unroll
        for (int kk = 0; kk < 32; kk++) {
            bf16x8 A = Acur;
            bf16x8 B0 = Bcur[0], B1 = Bcur[1], B2 = Bcur[2], B3 = Bcur[3];
            if (kk < 31) {
                Acur = *(const bf16x8*)(wp + (kk + 1) * 512 + lane * 8);
                int koff = (kk + 1) * 64 + l4 * 16;
#pragma unroll
                for (int bs = 0; bs < 4; bs++)
                    Bcur[bs] = *(const bf16x8*)(smem + brow[bs] + (koff ^ bswz[bs]));
            }
            acc[0] = __builtin_amdgcn_mfma_f32_16x16x32_bf16(A, B0, acc[0], 0, 0, 0);
            acc[1] = __builtin_amdgcn_mfma_f32_16x16x32_bf16(A, B1, acc[1], 0, 0, 0);
            acc[2] = __builtin_amdgcn_mfma_f32_16x16x32_bf16(A, B2, acc[2], 0, 0, 0);
            acc[3] = __builtin_amdgcn_mfma_f32_16x16x32_bf16(A, B3, acc[3], 0, 0, 0);
        }
    }

    // proj gather for this step
    const int tt = d ? (S - 1 - t) : t;
    const int j = jt * 32 + wid * 4 + l4;
    const f32x4* pp = (const f32x4*)projP + ((size_t)d * 1024 + j) * 128;
    f32x4 pj[4];
#pragma unroll
    for (int bs = 0; bs < 4; bs++) {
        int v = x[(b0 + bs * 16 + l15) * S + tt];
        pj[bs] = pp[v];
    }

    float* cp = cws + ((size_t)bid * 512 + tid) * 4;
    f32x4 cv = {0.f, 0.f, 0.f, 0.f};
    if (t > 0) cv = *(const f32x4*)cp;

    float hnv[4];
#pragma unroll
    for (int bs = 0; bs < 4; bs++) {
        float zg = acc[bs][0] + pj[bs][0];
        float zi = acc[bs][1] + pj[bs][1];
        float zf = acc[bs][2] + pj[bs][2];
        float zo = acc[bs][3] + pj[bs][3];
        float gg = tanh_fast(zg);
        float ii = sigf(zi);
        float ff = sigf(zf);
        float oo = sigf(zo);
        float cn = gg * ii + cv[bs] * ff;
        cv[bs] = cn;
        hnv[bs] = tanh_fast(cn) * oo;
    }
    *(f32x4*)cp = cv;

    // pure-register wave transpose via shfl (verified r6-r14 pattern)
    unsigned plo = (unsigned)f2bf(hnv[0]) | ((unsigned)f2bf(hnv[1]) << 16);
    unsigned phi = (unsigned)f2bf(hnv[2]) | ((unsigned)f2bf(hnv[3]) << 16);
    unsigned short o4[4];
#pragma unroll
    for (int p = 0; p < 4; p++) {
        int src = p * 16 + l15;
        unsigned vlo = __shfl(plo, src);
        unsigned vhi = __shfl(phi, src);
        unsigned sel = (l4 < 2) ? vlo : vhi;
        o4[p] = (l4 & 1) ? (unsigned short)(sel >> 16) : (unsigned short)(sel & 0xffffu);
    }
    u64 hv = (u64)o4[0] | ((u64)o4[1] << 16) | ((u64)o4[2] << 32) | ((u64)o4[3] << 48);
    __hip_bfloat16* hw = hbuf + (size_t)((t + 1) & 1) * 2 * B * H + dBH
                         + (size_t)(b0 + lane) * H + jt * 32 + wid * 4;
    *(u64a*)hw = hv;
}

// ---- head: logits + log_softmax (reads bf16 h, parity 0) ----
__global__ void head_kernel(const __hip_bfloat16* __restrict__ hbuf,
                            const float* __restrict__ p_w,
                            const float* __restrict__ p_b,
                            float* __restrict__ out) {
    int b = blockIdx.x;
    int lane = threadIdx.x;  // 64
    float part[C];
#pragma unroll
    for (int cc = 0; cc < C; cc++) part[cc] = 0.0f;
    for (int jj = lane; jj < 2 * H; jj += 64) {
        float hv = (jj < H)
            ? __bfloat162float(hbuf[(size_t)b * H + jj])
            : __bfloat162float(hbuf[(size_t)B * H + (size_t)b * H + jj - H]);
#pragma unroll
        for (int cc = 0; cc < C; cc++) part[cc] += hv * p_w[cc * 2 * H + jj];
    }
#pragma unroll
    for (int cc = 0; cc < C; cc++) {
        float v = part[cc];
        for (int off = 32; off; off >>= 1) v += __shfl_down(v, off);
        part[cc] = v;
    }
    if (lane == 0) {
        float lg[C];
        float m = -1e30f;
        for (int cc = 0; cc < C; cc++) {
            lg[cc] = part[cc] + p_b[cc];
            m = fmaxf(m, lg[cc]);
        }
        float s = 0.0f;
        for (int cc = 0; cc < C; cc++) s += expf(lg[cc] - m);
        float lse = logf(s) + m;
        for (int cc = 0; cc < C; cc++) out[b * C + cc] = lg[cc] - lse;
    }
}

extern "C" void kernel_launch(void* const* d_in, const int* in_sizes, int n_in,
                              void* d_out, int out_size, void* d_ws, size_t ws_size,
                              hipStream_t stream) {
    const int*   x     = (const int*)d_in[0];
    const float* embed = (const float*)d_in[1];
    const float* fwd_W = (const float*)d_in[2];
    const float* fwd_b = (const float*)d_in[3];
    const float* bwd_W = (const float*)d_in[4];
    const float* bwd_b = (const float*)d_in[5];
    const float* p_w   = (const float*)d_in[6];
    const float* p_b   = (const float*)d_in[7];
    float* outp = (float*)d_out;

    char* ws = (char*)d_ws;
    __hip_bfloat16* wF  = (__hip_bfloat16*)ws;  ws += (size_t)2 * 256 * 16384 * 2;    // 16 MB
    // 8 MB region shared in time: wxF (prep only) overlays cws (steps only)
    __hip_bfloat16* wxF = (__hip_bfloat16*)ws;
    float* cws = (float*)ws;                    ws += (size_t)2 * 256 * 8192 * 2;     // 8 MB
    unsigned short* ehl = (unsigned short*)ws;  ws += (size_t)2 * 128 * 512 * 2;      // 256 KB
    float* projP = (float*)ws;                  ws += (size_t)2 * 1024 * 128 * 4 * 4; // 4 MB
    __hip_bfloat16* hbuf = (__hip_bfloat16*)ws; ws += (size_t)2 * 2 * B * H * 2;      // 2 MB

    hipLaunchKernelGGL(prep_build, dim3(6400), dim3(256), 0, stream,
                       fwd_W, bwd_W, embed, wF, wxF, ehl);

    hipFuncSetAttribute((const void*)projp_mfma,
                        hipFuncAttributeMaxDynamicSharedMemorySize, 65536);
    hipLaunchKernelGGL(projp_mfma, dim3(256), dim3(256), 65536, stream,
                       wxF, ehl, fwd_b, bwd_b, projP);

    hipFuncSetAttribute((const void*)step_kernel,
                        hipFuncAttributeMaxDynamicSharedMemorySize, LDS_H);
    for (int t = 0; t < S; t++)
        hipLaunchKernelGGL(step_kernel, dim3(256), dim3(512), LDS_H, stream,
                           x, wF, projP, hbuf, cws, t);

    hipLaunchKernelGGL(head_kernel, dim3(B), dim3(64), 0, stream,
                       hbuf, p_w, p_b, outp);
}